// Round 6
// baseline (274.828 us; speedup 1.0000x reference)
//
#include <hip/hip_runtime.h>

#define NN 50000
#define NP 50176        // padded node stride (multiple of 256)
#define TT 518
#define KC 32
#define LL 163
#define HH 128
#define EE 1600000
#define NB 196          // node blocks: 196*256 = 50176 >= NN
#define NCOPY 8
#define UL 8            // l-values per thread in k_conv
#define XS (3*UL+29)    // 53 x-values per thread
#define NLC ((LL+UL-1)/UL)  // 21 l-chunks

// ---- chunked-LDS scatter (no global atomics) ----
#define CKN 4           // node chunks
#define CSZ 12544       // nodes/chunk (4*12544 = 50176), LDS acc = 50176 B
#define PSL 128         // edge slices (partials per chunk)
#define GSC (CKN*PSL)   // 512 blocks
#define ESL (EE/PSL)    // 12500 edges per slice (divisible by 4)

// deg partials: block (chunk=b&3, p=b>>2) scans slice p, bins col hits into
// LDS, flushes private partial with plain float4 stores.
__global__ __launch_bounds__(256) void k_deg_part(const int* __restrict__ col,
                                                  const float* __restrict__ ea,
                                                  float* __restrict__ part) {
  __shared__ float acc[CSZ];
  float4* acc4 = (float4*)acc;
  int tid = threadIdx.x;
  for (int j = tid; j < CSZ / 4; j += 256)
    acc4[j] = make_float4(0.f, 0.f, 0.f, 0.f);
  __syncthreads();
  int chunk = blockIdx.x & (CKN - 1);
  int base = chunk * CSZ;
  const int4*   c4p = (const int4*)col + (blockIdx.x >> 2) * (ESL / 4);
  const float4* a4p = (const float4*)ea + (blockIdx.x >> 2) * (ESL / 4);
  for (int i = tid; i < ESL / 4; i += 256) {
    int4   c4 = c4p[i];
    float4 a4 = a4p[i];
    unsigned jx = (unsigned)(c4.x - base);
    unsigned jy = (unsigned)(c4.y - base);
    unsigned jz = (unsigned)(c4.z - base);
    unsigned jw = (unsigned)(c4.w - base);
    if (jx < CSZ) atomicAdd(&acc[jx], a4.x);
    if (jy < CSZ) atomicAdd(&acc[jy], a4.y);
    if (jz < CSZ) atomicAdd(&acc[jz], a4.z);
    if (jw < CSZ) atomicAdd(&acc[jw], a4.w);
  }
  __syncthreads();
  float4* out4 = (float4*)(part + (size_t)blockIdx.x * CSZ);
  for (int j = tid; j < CSZ / 4; j += 256) out4[j] = acc4[j];
}

// dinv[i] = rsqrt(1 + sum_p degpart[p][i]); float4 per thread (CSZ%4==0 so
// a quad never straddles a chunk boundary; 4x fewer inst, 4x the MLP).
__global__ __launch_bounds__(256) void k_dinv2(const float* __restrict__ part,
                                               float* __restrict__ dinv) {
  int i4 = blockIdx.x * 256 + threadIdx.x;
  if (i4 >= NN / 4) return;
  int i = 4 * i4;
  int chunk = i / CSZ, j = i - chunk * CSZ;
  const float4* q = (const float4*)(part + (size_t)chunk * CSZ + j);
  float4 s = make_float4(1.f, 1.f, 1.f, 1.f);
#pragma unroll 8
  for (int p = 0; p < PSL; ++p) {
    float4 t = q[(size_t)p * (CKN * CSZ / 4)];
    s.x += t.x; s.y += t.y; s.z += t.z; s.w += t.w;
  }
  float4 d;
  d.x = rsqrtf(s.x); d.y = rsqrtf(s.y); d.z = rsqrtf(s.z); d.w = rsqrtf(s.w);
  ((float4*)dinv)[i4] = d;
}

// ev[e] = ea[e] * dinv[col[e]] — the gather hoisted OUT of the chunk loop
// (R5: coef_part redid all 1.6M gathers per chunk pass = 6.4M; now 1.6M once).
__global__ __launch_bounds__(256) void k_ev(const int* __restrict__ col,
                                            const float* __restrict__ ea,
                                            const float* __restrict__ dinv,
                                            float* __restrict__ ev) {
  int i = blockIdx.x * 256 + threadIdx.x;
  if (i < EE / 4) {
    int4   c4 = ((const int4*)col)[i];
    float4 a4 = ((const float4*)ea)[i];
    float4 r;
    r.x = a4.x * dinv[c4.x];
    r.y = a4.y * dinv[c4.y];
    r.z = a4.z * dinv[c4.z];
    r.w = a4.w * dinv[c4.w];
    ((float4*)ev)[i] = r;
  }
}

// coef partials: acc[row] += ev[e].  (dinv[row] factor folded into k_csum2.)
__global__ __launch_bounds__(256) void k_coef_part(const int* __restrict__ row,
                                                   const float* __restrict__ ev,
                                                   float* __restrict__ part) {
  __shared__ float acc[CSZ];
  float4* acc4 = (float4*)acc;
  int tid = threadIdx.x;
  for (int j = tid; j < CSZ / 4; j += 256)
    acc4[j] = make_float4(0.f, 0.f, 0.f, 0.f);
  __syncthreads();
  int chunk = blockIdx.x & (CKN - 1);
  int base = chunk * CSZ;
  const int4*   r4p = (const int4*)row + (blockIdx.x >> 2) * (ESL / 4);
  const float4* e4p = (const float4*)ev + (blockIdx.x >> 2) * (ESL / 4);
  for (int i = tid; i < ESL / 4; i += 256) {
    int4   r4 = r4p[i];
    float4 e4 = e4p[i];
    unsigned jx = (unsigned)(r4.x - base);
    unsigned jy = (unsigned)(r4.y - base);
    unsigned jz = (unsigned)(r4.z - base);
    unsigned jw = (unsigned)(r4.w - base);
    if (jx < CSZ) atomicAdd(&acc[jx], e4.x);
    if (jy < CSZ) atomicAdd(&acc[jy], e4.y);
    if (jz < CSZ) atomicAdd(&acc[jz], e4.z);
    if (jw < CSZ) atomicAdd(&acc[jw], e4.w);
  }
  __syncthreads();
  float4* out4 = (float4*)(part + (size_t)blockIdx.x * CSZ);
  for (int j = tid; j < CSZ / 4; j += 256) out4[j] = acc4[j];
}

// c[i] = dinv[i]^2 + dinv[i] * sum_p coefpart[p][i]; float4 per thread.
__global__ __launch_bounds__(256) void k_csum2(const float* __restrict__ part,
                                               const float* __restrict__ dinv,
                                               float* __restrict__ c) {
  int i4 = blockIdx.x * 256 + threadIdx.x;
  if (i4 >= NN / 4) return;
  int i = 4 * i4;
  int chunk = i / CSZ, j = i - chunk * CSZ;
  const float4* q = (const float4*)(part + (size_t)chunk * CSZ + j);
  float4 s = make_float4(0.f, 0.f, 0.f, 0.f);
#pragma unroll 8
  for (int p = 0; p < PSL; ++p) {
    float4 t = q[(size_t)p * (CKN * CSZ / 4)];
    s.x += t.x; s.y += t.y; s.z += t.z; s.w += t.w;
  }
  float4 d = ((const float4*)dinv)[i4];
  float4 r;
  r.x = d.x * d.x + d.x * s.x;
  r.y = d.y * d.y + d.y * s.y;
  r.z = d.z * d.z + d.z * s.z;
  r.w = d.w * d.w + d.w * s.w;
  ((float4*)c)[i4] = r;
}

// ---- fallback path (R4 global-atomic version) if ws is too small ----
__global__ __launch_bounds__(256) void k_deg(const int* __restrict__ col,
                                             const float* __restrict__ ea,
                                             float* __restrict__ deg8) {
  int i = blockIdx.x * 256 + threadIdx.x;
  float* d = deg8 + (blockIdx.x & 7) * NP;
  if (i < EE / 4) {
    int4   c4 = ((const int4*)col)[i];
    float4 a4 = ((const float4*)ea)[i];
    atomicAdd(&d[c4.x], a4.x);
    atomicAdd(&d[c4.y], a4.y);
    atomicAdd(&d[c4.z], a4.z);
    atomicAdd(&d[c4.w], a4.w);
  }
}
__global__ __launch_bounds__(256) void k_dinv(const float* __restrict__ deg8,
                                              float* __restrict__ dinv) {
  int i = blockIdx.x * 256 + threadIdx.x;
  if (i < NN) {
    float s = 1.0f;
#pragma unroll
    for (int j = 0; j < NCOPY; ++j) s += deg8[j * NP + i];
    dinv[i] = rsqrtf(s);
  }
}
__global__ __launch_bounds__(256) void k_coef(const int* __restrict__ row,
                                              const int* __restrict__ col,
                                              const float* __restrict__ ea,
                                              const float* __restrict__ dinv,
                                              float* __restrict__ coef8) {
  int i = blockIdx.x * 256 + threadIdx.x;
  float* cf = coef8 + (blockIdx.x & 7) * NP;
  if (i < EE / 4) {
    int4   r4 = ((const int4*)row)[i];
    int4   c4 = ((const int4*)col)[i];
    float4 a4 = ((const float4*)ea)[i];
    atomicAdd(&cf[r4.x], a4.x * dinv[c4.x] * dinv[r4.x]);
    atomicAdd(&cf[r4.y], a4.y * dinv[c4.y] * dinv[r4.y]);
    atomicAdd(&cf[r4.z], a4.z * dinv[c4.z] * dinv[r4.z]);
    atomicAdd(&cf[r4.w], a4.w * dinv[c4.w] * dinv[r4.w]);
  }
}
__global__ __launch_bounds__(256) void k_csum(const float* __restrict__ coef8,
                                              const float* __restrict__ dinv,
                                              float* __restrict__ c) {
  int i = blockIdx.x * 256 + threadIdx.x;
  if (i < NN) {
    float di = dinv[i];
    float s = di * di;
#pragma unroll
    for (int j = 0; j < NCOPY; ++j) s += coef8[j * NP + i];
    c[i] = s;
  }
}

// v[l] += sum_n c[n]*relu(conv(x,w)+b)[l].  Batch mapping: thread = (node,
// 8 consecutive l's); all 53 x-loads + 8 w-loads independent, pinned above
// compute via sched_barrier(0). Unchanged since R4 (proven).
__global__ __launch_bounds__(256, 4) void k_conv(const float* __restrict__ x,
                                                 const float* __restrict__ cw,
                                                 const float* __restrict__ cb,
                                                 const float* __restrict__ c,
                                                 float* __restrict__ v) {
  __shared__ float vloc[UL];
  int tid = threadIdx.x;
  if (tid < UL) vloc[tid] = 0.f;
  __syncthreads();

  int nb = blockIdx.x % NB;
  int lc = blockIdx.x / NB;        // 0..20
  int n = nb * 256 + tid;
  int nc = n < NN ? n : NN - 1;    // clamp for safe loads; cn=0 kills contrib
  float cn = n < NN ? c[n] : 0.f;
  float bn = cb[nc];

  int l0 = lc * UL;
  int t0 = 3 * l0;

  float w[KC];
  const float4* w4 = (const float4*)(cw + (size_t)nc * KC);
#pragma unroll
  for (int k = 0; k < KC / 4; ++k) {
    float4 t = w4[k];
    w[4 * k] = t.x; w[4 * k + 1] = t.y; w[4 * k + 2] = t.z; w[4 * k + 3] = t.w;
  }
  const float* xp = x + nc;
  float xs[XS];
#pragma unroll
  for (int j = 0; j < XS; ++j) {
    int t = t0 + j;
    int tc = t < TT ? t : TT - 1;  // only lc==20 clamps; uniform
    xs[j] = xp[(size_t)tc * NN];
  }
  __builtin_amdgcn_sched_barrier(0);   // loads stay ABOVE, compute BELOW

  float acc[UL];
#pragma unroll
  for (int u = 0; u < UL; ++u) {
    float h0 = 0.f, h1 = 0.f, h2 = 0.f, h3 = 0.f;
#pragma unroll
    for (int k = 0; k < KC; k += 4) {
      h0 += xs[3 * u + k    ] * w[k];
      h1 += xs[3 * u + k + 1] * w[k + 1];
      h2 += xs[3 * u + k + 2] * w[k + 2];
      h3 += xs[3 * u + k + 3] * w[k + 3];
    }
    float hv = (h0 + h1) + (h2 + h3) + bn;
    hv = hv > 0.f ? hv : 0.f;
    acc[u] = cn * hv;
  }

  int lane = tid & 63;
#pragma unroll
  for (int u = 0; u < UL; ++u) {
    float val = acc[u];
#pragma unroll
    for (int off = 1; off < 64; off <<= 1) val += __shfl_xor(val, off, 64);
    if (lane == 0 && l0 + u < LL) atomicAdd(&vloc[u], val);
  }
  __syncthreads();
  if (tid < UL && l0 + tid < LL) atomicAdd(&v[l0 + tid], vloc[tid]);
}

// out[h] = (sum_l v[l]*W[l][h]) / N + gcn_b[h]
__global__ __launch_bounds__(128) void k_out(const float* __restrict__ v,
                                             const float* __restrict__ W,
                                             const float* __restrict__ b,
                                             float* __restrict__ out) {
  int h = threadIdx.x;
  float s = 0.f;
  for (int l = 0; l < LL; ++l) s += v[l] * W[l * HH + h];
  out[h] = s * (1.0f / NN) + b[h];
}

extern "C" void kernel_launch(void* const* d_in, const int* in_sizes, int n_in,
                              void* d_out, int out_size, void* d_ws, size_t ws_size,
                              hipStream_t stream) {
  const float* x  = (const float*)d_in[0];
  const int*   ei = (const int*)d_in[1];
  const float* ea = (const float*)d_in[2];
  const float* cw = (const float*)d_in[3];
  const float* cb = (const float*)d_in[4];
  const float* gW = (const float*)d_in[5];
  const float* gb = (const float*)d_in[6];
  float* out = (float*)d_out;

  const int* row = ei;
  const int* col = ei + EE;
  float* ws = (float*)d_ws;

  size_t need_new = ((size_t)GSC * CSZ + EE + 256 + 2 * NP) * sizeof(float);
  if (ws_size >= need_new) {
    float* part = ws;                          // GSC*CSZ floats (deg then coef)
    float* ev   = ws + (size_t)GSC * CSZ;      // EE floats
    float* v    = ev + EE;                     // 256 floats
    float* dinv = v + 256;                     // NP floats
    float* c    = dinv + NP;                   // NP floats
    hipMemsetAsync(v, 0, 256 * sizeof(float), stream);
    int rgrid = (NN / 4 + 255) / 256;          // 49
    int egrid = (EE / 4 + 255) / 256;          // 1563
    k_deg_part <<<GSC, 256, 0, stream>>>(col, ea, part);
    k_dinv2    <<<rgrid, 256, 0, stream>>>(part, dinv);
    k_ev       <<<egrid, 256, 0, stream>>>(col, ea, dinv, ev);
    k_coef_part<<<GSC, 256, 0, stream>>>(row, ev, part);
    k_csum2    <<<rgrid, 256, 0, stream>>>(part, dinv, c);
    k_conv     <<<NB * NLC, 256, 0, stream>>>(x, cw, cb, c, v);
    k_out      <<<1, 128, 0, stream>>>(v, gW, gb, out);
  } else {
    float* deg8  = ws;
    float* coef8 = ws + NCOPY * NP;
    float* v     = ws + 2 * NCOPY * NP;
    float* dinv  = ws + 2 * NCOPY * NP + 256;
    float* c     = ws + 2 * NCOPY * NP + 256 + NP;
    hipMemsetAsync(deg8, 0, (2 * NCOPY * NP + 256) * sizeof(float), stream);
    int egrid = (EE / 4 + 255) / 256;
    k_deg <<<egrid, 256, 0, stream>>>(col, ea, deg8);
    k_dinv<<<NB, 256, 0, stream>>>(deg8, dinv);
    k_coef<<<egrid, 256, 0, stream>>>(row, col, ea, dinv, coef8);
    k_csum<<<NB, 256, 0, stream>>>(coef8, dinv, c);
    k_conv<<<NB * NLC, 256, 0, stream>>>(x, cw, cb, c, v);
    k_out <<<1, 128, 0, stream>>>(v, gW, gb, out);
  }
}

// Round 7
// 269.755 us; speedup vs baseline: 1.0188x; 1.0188x over previous
//
#include <hip/hip_runtime.h>

#define NN 50000
#define NP 50176        // padded node stride (multiple of 256)
#define TT 518
#define KC 32
#define LL 163
#define HH 128
#define EE 1600000
#define NB 196          // node blocks: 196*256 = 50176 >= NN
#define NCOPY 8
#define UL 12           // l-values per thread in k_conv (R7: 8->12, cuts x
                        // re-read 2.2x->1.8x and w rebroadcast 21x->14x)
#define XS (3*UL+29)    // 65 x-values per thread
#define NLC ((LL+UL-1)/UL)  // 14 l-chunks

// ---- chunked-LDS scatter (no global atomics) ----
#define CKN 4           // node chunks
#define CSZ 12544       // nodes/chunk (4*12544 = 50176), LDS acc = 50176 B
#define PSL 128         // edge slices (partials per chunk)
#define GSC (CKN*PSL)   // 512 blocks
#define ESL (EE/PSL)    // 12500 edges per slice (divisible by 4)

// deg partials: block (chunk=b&3, p=b>>2) scans slice p, bins col hits into
// LDS, flushes private partial with plain float4 stores.
__global__ __launch_bounds__(256) void k_deg_part(const int* __restrict__ col,
                                                  const float* __restrict__ ea,
                                                  float* __restrict__ part) {
  __shared__ float acc[CSZ];
  float4* acc4 = (float4*)acc;
  int tid = threadIdx.x;
  for (int j = tid; j < CSZ / 4; j += 256)
    acc4[j] = make_float4(0.f, 0.f, 0.f, 0.f);
  __syncthreads();
  int chunk = blockIdx.x & (CKN - 1);
  int base = chunk * CSZ;
  const int4*   c4p = (const int4*)col + (blockIdx.x >> 2) * (ESL / 4);
  const float4* a4p = (const float4*)ea + (blockIdx.x >> 2) * (ESL / 4);
  for (int i = tid; i < ESL / 4; i += 256) {
    int4   c4 = c4p[i];
    float4 a4 = a4p[i];
    unsigned jx = (unsigned)(c4.x - base);
    unsigned jy = (unsigned)(c4.y - base);
    unsigned jz = (unsigned)(c4.z - base);
    unsigned jw = (unsigned)(c4.w - base);
    if (jx < CSZ) atomicAdd(&acc[jx], a4.x);
    if (jy < CSZ) atomicAdd(&acc[jy], a4.y);
    if (jz < CSZ) atomicAdd(&acc[jz], a4.z);
    if (jw < CSZ) atomicAdd(&acc[jw], a4.w);
  }
  __syncthreads();
  float4* out4 = (float4*)(part + (size_t)blockIdx.x * CSZ);
  for (int j = tid; j < CSZ / 4; j += 256) out4[j] = acc4[j];
}

// dinv[i] = rsqrt(1 + sum_p degpart[p][i]); float4 per thread. Tail threads
// (i4 >= NN/4) zero the v accumulator — replaces a separate memset dispatch.
__global__ __launch_bounds__(256) void k_dinv2(const float* __restrict__ part,
                                               float* __restrict__ dinv,
                                               float* __restrict__ v) {
  int i4 = blockIdx.x * 256 + threadIdx.x;
  if (i4 >= NN / 4) {
    int j = i4 - NN / 4;
    if (j < 64) ((float4*)v)[j] = make_float4(0.f, 0.f, 0.f, 0.f);
    return;
  }
  int i = 4 * i4;
  int chunk = i / CSZ, j = i - chunk * CSZ;
  const float4* q = (const float4*)(part + (size_t)chunk * CSZ + j);
  float4 s = make_float4(1.f, 1.f, 1.f, 1.f);
#pragma unroll 8
  for (int p = 0; p < PSL; ++p) {
    float4 t = q[(size_t)p * (CKN * CSZ / 4)];
    s.x += t.x; s.y += t.y; s.z += t.z; s.w += t.w;
  }
  float4 d;
  d.x = rsqrtf(s.x); d.y = rsqrtf(s.y); d.z = rsqrtf(s.z); d.w = rsqrtf(s.w);
  ((float4*)dinv)[i4] = d;
}

// coef partials: acc[row] += ea*dinv[col], gather INLINE (R6 lesson: dinv is
// 200 KB = L2-resident, redundant gathers are ~free; hoisting them through a
// 19 MB ev stream was a net loss). dinv[row] factor folded into k_csum2.
__global__ __launch_bounds__(256) void k_coef_part(const int* __restrict__ row,
                                                   const int* __restrict__ col,
                                                   const float* __restrict__ ea,
                                                   const float* __restrict__ dinv,
                                                   float* __restrict__ part) {
  __shared__ float acc[CSZ];
  float4* acc4 = (float4*)acc;
  int tid = threadIdx.x;
  for (int j = tid; j < CSZ / 4; j += 256)
    acc4[j] = make_float4(0.f, 0.f, 0.f, 0.f);
  __syncthreads();
  int chunk = blockIdx.x & (CKN - 1);
  int base = chunk * CSZ;
  const int4*   r4p = (const int4*)row + (blockIdx.x >> 2) * (ESL / 4);
  const int4*   c4p = (const int4*)col + (blockIdx.x >> 2) * (ESL / 4);
  const float4* a4p = (const float4*)ea + (blockIdx.x >> 2) * (ESL / 4);
  for (int i = tid; i < ESL / 4; i += 256) {
    int4   r4 = r4p[i];
    int4   c4 = c4p[i];
    float4 a4 = a4p[i];
    unsigned jx = (unsigned)(r4.x - base);
    unsigned jy = (unsigned)(r4.y - base);
    unsigned jz = (unsigned)(r4.z - base);
    unsigned jw = (unsigned)(r4.w - base);
    if (jx < CSZ) atomicAdd(&acc[jx], a4.x * dinv[c4.x]);
    if (jy < CSZ) atomicAdd(&acc[jy], a4.y * dinv[c4.y]);
    if (jz < CSZ) atomicAdd(&acc[jz], a4.z * dinv[c4.z]);
    if (jw < CSZ) atomicAdd(&acc[jw], a4.w * dinv[c4.w]);
  }
  __syncthreads();
  float4* out4 = (float4*)(part + (size_t)blockIdx.x * CSZ);
  for (int j = tid; j < CSZ / 4; j += 256) out4[j] = acc4[j];
}

// c[i] = dinv[i]^2 + dinv[i] * sum_p coefpart[p][i]; float4 per thread.
__global__ __launch_bounds__(256) void k_csum2(const float* __restrict__ part,
                                               const float* __restrict__ dinv,
                                               float* __restrict__ c) {
  int i4 = blockIdx.x * 256 + threadIdx.x;
  if (i4 >= NN / 4) return;
  int i = 4 * i4;
  int chunk = i / CSZ, j = i - chunk * CSZ;
  const float4* q = (const float4*)(part + (size_t)chunk * CSZ + j);
  float4 s = make_float4(0.f, 0.f, 0.f, 0.f);
#pragma unroll 8
  for (int p = 0; p < PSL; ++p) {
    float4 t = q[(size_t)p * (CKN * CSZ / 4)];
    s.x += t.x; s.y += t.y; s.z += t.z; s.w += t.w;
  }
  float4 d = ((const float4*)dinv)[i4];
  float4 r;
  r.x = d.x * d.x + d.x * s.x;
  r.y = d.y * d.y + d.y * s.y;
  r.z = d.z * d.z + d.z * s.z;
  r.w = d.w * d.w + d.w * s.w;
  ((float4*)c)[i4] = r;
}

// ---- fallback path (global-atomic version) if ws is too small ----
__global__ __launch_bounds__(256) void k_deg(const int* __restrict__ col,
                                             const float* __restrict__ ea,
                                             float* __restrict__ deg8) {
  int i = blockIdx.x * 256 + threadIdx.x;
  float* d = deg8 + (blockIdx.x & 7) * NP;
  if (i < EE / 4) {
    int4   c4 = ((const int4*)col)[i];
    float4 a4 = ((const float4*)ea)[i];
    atomicAdd(&d[c4.x], a4.x);
    atomicAdd(&d[c4.y], a4.y);
    atomicAdd(&d[c4.z], a4.z);
    atomicAdd(&d[c4.w], a4.w);
  }
}
__global__ __launch_bounds__(256) void k_dinv(const float* __restrict__ deg8,
                                              float* __restrict__ dinv) {
  int i = blockIdx.x * 256 + threadIdx.x;
  if (i < NN) {
    float s = 1.0f;
#pragma unroll
    for (int j = 0; j < NCOPY; ++j) s += deg8[j * NP + i];
    dinv[i] = rsqrtf(s);
  }
}
__global__ __launch_bounds__(256) void k_coef(const int* __restrict__ row,
                                              const int* __restrict__ col,
                                              const float* __restrict__ ea,
                                              const float* __restrict__ dinv,
                                              float* __restrict__ coef8) {
  int i = blockIdx.x * 256 + threadIdx.x;
  float* cf = coef8 + (blockIdx.x & 7) * NP;
  if (i < EE / 4) {
    int4   r4 = ((const int4*)row)[i];
    int4   c4 = ((const int4*)col)[i];
    float4 a4 = ((const float4*)ea)[i];
    atomicAdd(&cf[r4.x], a4.x * dinv[c4.x] * dinv[r4.x]);
    atomicAdd(&cf[r4.y], a4.y * dinv[c4.y] * dinv[r4.y]);
    atomicAdd(&cf[r4.z], a4.z * dinv[c4.z] * dinv[r4.z]);
    atomicAdd(&cf[r4.w], a4.w * dinv[c4.w] * dinv[r4.w]);
  }
}
__global__ __launch_bounds__(256) void k_csum(const float* __restrict__ coef8,
                                              const float* __restrict__ dinv,
                                              float* __restrict__ c) {
  int i = blockIdx.x * 256 + threadIdx.x;
  if (i < NN) {
    float di = dinv[i];
    float s = di * di;
#pragma unroll
    for (int j = 0; j < NCOPY; ++j) s += coef8[j * NP + i];
    c[i] = s;
  }
}

// v[l] += sum_n c[n]*relu(conv(x,w)+b)[l].  Batch mapping: thread = (node,
// UL consecutive l's); all 65 x-loads + 8 w-loads independent, pinned above
// compute via sched_barrier(0). UL=12 @ (256,3): ~121 VGPR < 170 cap.
__global__ __launch_bounds__(256, 3) void k_conv(const float* __restrict__ x,
                                                 const float* __restrict__ cw,
                                                 const float* __restrict__ cb,
                                                 const float* __restrict__ c,
                                                 float* __restrict__ v) {
  __shared__ float vloc[UL];
  int tid = threadIdx.x;
  if (tid < UL) vloc[tid] = 0.f;
  __syncthreads();

  int nb = blockIdx.x % NB;
  int lc = blockIdx.x / NB;        // 0..13
  int n = nb * 256 + tid;
  int nc = n < NN ? n : NN - 1;    // clamp for safe loads; cn=0 kills contrib
  float cn = n < NN ? c[n] : 0.f;
  float bn = cb[nc];

  int l0 = lc * UL;
  int t0 = 3 * l0;

  float w[KC];
  const float4* w4 = (const float4*)(cw + (size_t)nc * KC);
#pragma unroll
  for (int k = 0; k < KC / 4; ++k) {
    float4 t = w4[k];
    w[4 * k] = t.x; w[4 * k + 1] = t.y; w[4 * k + 2] = t.z; w[4 * k + 3] = t.w;
  }
  const float* xp = x + nc;
  float xs[XS];
#pragma unroll
  for (int j = 0; j < XS; ++j) {
    int t = t0 + j;
    int tc = t < TT ? t : TT - 1;  // only last lc clamps; uniform
    xs[j] = xp[(size_t)tc * NN];
  }
  __builtin_amdgcn_sched_barrier(0);   // loads stay ABOVE, compute BELOW

  float acc[UL];
#pragma unroll
  for (int u = 0; u < UL; ++u) {
    float h0 = 0.f, h1 = 0.f, h2 = 0.f, h3 = 0.f;
#pragma unroll
    for (int k = 0; k < KC; k += 4) {
      h0 += xs[3 * u + k    ] * w[k];
      h1 += xs[3 * u + k + 1] * w[k + 1];
      h2 += xs[3 * u + k + 2] * w[k + 2];
      h3 += xs[3 * u + k + 3] * w[k + 3];
    }
    float hv = (h0 + h1) + (h2 + h3) + bn;
    hv = hv > 0.f ? hv : 0.f;
    acc[u] = cn * hv;
  }

  int lane = tid & 63;
#pragma unroll
  for (int u = 0; u < UL; ++u) {
    if (l0 + u >= LL) break;       // uniform (last lc tail)
    float val = acc[u];
#pragma unroll
    for (int off = 1; off < 64; off <<= 1) val += __shfl_xor(val, off, 64);
    if (lane == 0) atomicAdd(&vloc[u], val);
  }
  __syncthreads();
  if (tid < UL && l0 + tid < LL) atomicAdd(&v[l0 + tid], vloc[tid]);
}

// out[h] = (sum_l v[l]*W[l][h]) / N + gcn_b[h]
__global__ __launch_bounds__(128) void k_out(const float* __restrict__ v,
                                             const float* __restrict__ W,
                                             const float* __restrict__ b,
                                             float* __restrict__ out) {
  int h = threadIdx.x;
  float s = 0.f;
  for (int l = 0; l < LL; ++l) s += v[l] * W[l * HH + h];
  out[h] = s * (1.0f / NN) + b[h];
}

extern "C" void kernel_launch(void* const* d_in, const int* in_sizes, int n_in,
                              void* d_out, int out_size, void* d_ws, size_t ws_size,
                              hipStream_t stream) {
  const float* x  = (const float*)d_in[0];
  const int*   ei = (const int*)d_in[1];
  const float* ea = (const float*)d_in[2];
  const float* cw = (const float*)d_in[3];
  const float* cb = (const float*)d_in[4];
  const float* gW = (const float*)d_in[5];
  const float* gb = (const float*)d_in[6];
  float* out = (float*)d_out;

  const int* row = ei;
  const int* col = ei + EE;
  float* ws = (float*)d_ws;

  size_t need_new = ((size_t)GSC * CSZ + 256 + 2 * NP) * sizeof(float);
  if (ws_size >= need_new) {
    float* part = ws;                          // GSC*CSZ floats (deg then coef)
    float* v    = ws + (size_t)GSC * CSZ;      // 256 floats
    float* dinv = v + 256;                     // NP floats
    float* c    = dinv + NP;                   // NP floats
    int rgrid = (NN / 4 + 64 + 255) / 256;     // 50 (incl. v-zero tail)
    k_deg_part <<<GSC, 256, 0, stream>>>(col, ea, part);
    k_dinv2    <<<rgrid, 256, 0, stream>>>(part, dinv, v);
    k_coef_part<<<GSC, 256, 0, stream>>>(row, col, ea, dinv, part);
    k_csum2    <<<rgrid, 256, 0, stream>>>(part, dinv, c);
    k_conv     <<<NB * NLC, 256, 0, stream>>>(x, cw, cb, c, v);
    k_out      <<<1, 128, 0, stream>>>(v, gW, gb, out);
  } else {
    float* deg8  = ws;
    float* coef8 = ws + NCOPY * NP;
    float* v     = ws + 2 * NCOPY * NP;
    float* dinv  = ws + 2 * NCOPY * NP + 256;
    float* c     = ws + 2 * NCOPY * NP + 256 + NP;
    hipMemsetAsync(deg8, 0, (2 * NCOPY * NP + 256) * sizeof(float), stream);
    int egrid = (EE / 4 + 255) / 256;
    k_deg <<<egrid, 256, 0, stream>>>(col, ea, deg8);
    k_dinv<<<NB, 256, 0, stream>>>(deg8, dinv);
    k_coef<<<egrid, 256, 0, stream>>>(row, col, ea, dinv, coef8);
    k_csum<<<NB, 256, 0, stream>>>(coef8, dinv, c);
    k_conv<<<NB * NLC, 256, 0, stream>>>(x, cw, cb, c, v);
    k_out <<<1, 128, 0, stream>>>(v, gW, gb, out);
  }
}